// Round 7
// baseline (382.180 us; speedup 1.0000x reference)
//
#include <hip/hip_runtime.h>

#define B_     8
#define N_     16384
#define F_     64
#define E_     262144
#define C_     10
#define NF_    (N_ * F_)        // 1048576
#define BN_    (B_ * N_)        // 131072
#define BNF_   (B_ * N_ * F_)   // 8388608
#define BE_    (B_ * E_)        // 2097152
#define CAP_   48               // padded CSR row capacity; P(Poisson(16) >= 48) ~ 6e-11
#define CHUNK_ 4096             // edges per build workgroup
#define NCH_   (E_ / CHUNK_)    // 64 chunks per batch
#define NW_    (N_ / 4)         // 4096 packed-u8 words per batch
#define EPS_   1e-5f

typedef float v4f __attribute__((ext_vector_type(4)));

// ---------------- Build phase A: per-chunk privatized counts ----------------
__global__ __launch_bounds__(256) void k_count(const int* __restrict__ src,
                                               const int* __restrict__ dst,
                                               unsigned int* __restrict__ partO,
                                               unsigned int* __restrict__ partI) {
    __shared__ unsigned int pO[NW_];  // 16 KB
    __shared__ unsigned int pI[NW_];  // 16 KB
    int t = threadIdx.x;
    int b = blockIdx.x & 7, c = blockIdx.x >> 3;
    for (int i = t; i < NW_; i += 256) { pO[i] = 0; pI[i] = 0; }
    __syncthreads();
    const int* sb = src + (size_t)b * E_ + (size_t)c * CHUNK_;
    const int* db = dst + (size_t)b * E_ + (size_t)c * CHUNK_;
    for (int i = t; i < CHUNK_; i += 256) {
        int s = sb[i], d = db[i];
        atomicAdd(&pO[s >> 2], 1u << ((s & 3) * 8));
        atomicAdd(&pI[d >> 2], 1u << ((d & 3) * 8));
    }
    __syncthreads();
    size_t base = (size_t)(b * NCH_ + c) * NW_;
    for (int i = t; i < NW_; i += 256) {
        partO[base + i] = pO[i];
        partI[base + i] = pI[i];
    }
}

// ---------------- Build phase B: packed prefix over chunks + degrees --------
__global__ __launch_bounds__(256) void k_offsets(const unsigned int* __restrict__ partO,
                                                 const unsigned int* __restrict__ partI,
                                                 unsigned int* __restrict__ baseArr,
                                                 float* __restrict__ degOr,
                                                 float* __restrict__ degIr,
                                                 int* __restrict__ cntI_g) {
    int gw = blockIdx.x * 256 + threadIdx.x;  // word id in [0, BN_/4)
    int b = gw >> 12;
    int rw = gw & 4095;
    unsigned int sumI = 0, sumO = 0;
    for (int c = 0; c < NCH_; ++c) {
        size_t idx = (size_t)(b * NCH_ + c) * NW_ + rw;
        unsigned int wI = partI[idx];
        baseArr[idx] = sumI;  // exclusive prefix, packed u8 lanes
        sumI += wI;
        sumO += partO[idx];
    }
    int row0 = gw * 4;
#pragma unroll
    for (int r = 0; r < 4; ++r) {
        unsigned int ci = (sumI >> (r * 8)) & 0xFFu;
        unsigned int co = (sumO >> (r * 8)) & 0xFFu;
        degIr[row0 + r] = rsqrtf(fmaxf((float)ci, 1.0f));
        degOr[row0 + r] = rsqrtf(fmaxf((float)co, 1.0f));
        cntI_g[row0 + r] = (int)ci;
    }
}

// ---------------- Build phase C: deterministic-offset CSR fill --------------
__global__ __launch_bounds__(256) void k_fill(const int* __restrict__ src,
                                              const int* __restrict__ dst,
                                              const unsigned int* __restrict__ baseArr,
                                              unsigned short* __restrict__ csr) {
    __shared__ unsigned int cur[NW_];  // 16 KB
    __shared__ unsigned int bw[NW_];   // 16 KB
    int t = threadIdx.x;
    int b = blockIdx.x & 7, c = blockIdx.x >> 3;
    size_t pbase = (size_t)(b * NCH_ + c) * NW_;
    for (int i = t; i < NW_; i += 256) { cur[i] = 0; bw[i] = baseArr[pbase + i]; }
    __syncthreads();
    const int* sb = src + (size_t)b * E_ + (size_t)c * CHUNK_;
    const int* db = dst + (size_t)b * E_ + (size_t)c * CHUNK_;
    unsigned short* cb = csr + (size_t)b * N_ * CAP_;
    for (int i = t; i < CHUNK_; i += 256) {
        int s = sb[i], d = db[i];
        unsigned int sh = (d & 3) * 8;
        unsigned int old = atomicAdd(&cur[d >> 2], 1u << sh);
        unsigned int pos = ((old >> sh) & 0xFFu) + ((bw[d >> 2] >> sh) & 0xFFu);
        if (pos < CAP_) cb[d * CAP_ + pos] = (unsigned short)s;
    }
}

// ---------------- Fused conv: gather + (row @ W + bias) + scalings ----------
// 256 threads = 4 waves; wave handles 4 rows. Lane layout: r = lane>>4 (row),
// c = lane&15 (float4 feature group). Inner loop: half-segments of 8 edges
// with all 8 predicated dwordx4 loads issued BEFORE the FMA block (deep MLP),
// wave-uniform skip every 8 edges. Output via non-temporal stores (keep the
// XCD L2 for the x slice); CSR via non-temporal loads.
template <bool PRE, bool RELU, bool POST>
__global__ __launch_bounds__(256, 6) void k_conv(
        const int* __restrict__ cnt, const unsigned short* __restrict__ csr,
        const float* __restrict__ xs, const float* __restrict__ preE,
        const float* __restrict__ preR, const float* __restrict__ postR,
        const float* __restrict__ W, const float* __restrict__ bias,
        float* __restrict__ out) {
    __shared__ float4 Wl[64 * 16];  // 16 KB, [f][c]
    int t = threadIdx.x;
    const float4* Wg = (const float4*)W;
    for (int i = t; i < 1024; i += 256) Wl[i] = Wg[i];
    __syncthreads();

    int lane = t & 63;
    int wave = t >> 6;
    int c = lane & 15;
    int b = blockIdx.x & 7;  // XCD swizzle: one batch per XCD -> L2-resident xs
    int row = (blockIdx.x >> 3) * 16 + wave * 4 + (lane >> 4);
    int wid = b * N_ + row;
    const float* xb = xs + (size_t)b * NF_;
    int lb = lane & 48;
    int co = c * 4;

    int n = cnt[wid];
    if (n > CAP_) n = CAP_;
    size_t cb = (size_t)wid * CAP_;
    int e0 = __builtin_nontemporal_load(&csr[cb + c]) & 0x3FFF;
    int e1 = __builtin_nontemporal_load(&csr[cb + 16 + c]) & 0x3FFF;
    int e2 = __builtin_nontemporal_load(&csr[cb + 32 + c]) & 0x3FFF;
    float d0 = 0.0f, d1 = 0.0f, d2 = 0.0f;
    if (PRE) {
        const float* pe = preE + b * N_;
        d0 = pe[e0]; d1 = pe[e1]; d2 = pe[e2];
    }
    float pre = preR[wid];                      // early: overlaps gather
    const float4 bv = ((const float4*)bias)[c];
    int m = n;  // wave-uniform max count across the 4 rows
    m = max(m, __shfl_xor(m, 16));
    m = max(m, __shfl_xor(m, 32));

    float ax = 0.0f, ay = 0.0f, az = 0.0f, aw = 0.0f;

    // 8 edges: issue all loads (per-lane predicated), then all FMAs.
#define HALF(EREG, DREG, KOFF, JBASE)                                          \
    {                                                                          \
        float4 v[8];                                                           \
        float wv[8];                                                           \
        int rem = n - (KOFF);                                                  \
        _Pragma("unroll")                                                      \
        for (int jj = 0; jj < 8; ++jj) {                                       \
            int s = __shfl(EREG, lb + (JBASE) + jj);                           \
            if (PRE) wv[jj] = __shfl(DREG, lb + (JBASE) + jj);                 \
            v[jj] = make_float4(0.0f, 0.0f, 0.0f, 0.0f);                       \
            if (jj < rem) v[jj] = *(const float4*)(xb + s * 64 + co);          \
        }                                                                      \
        _Pragma("unroll")                                                      \
        for (int jj = 0; jj < 8; ++jj) {                                       \
            if (PRE) {                                                         \
                ax = fmaf(v[jj].x, wv[jj], ax); ay = fmaf(v[jj].y, wv[jj], ay);\
                az = fmaf(v[jj].z, wv[jj], az); aw = fmaf(v[jj].w, wv[jj], aw);\
            } else {                                                           \
                ax += v[jj].x; ay += v[jj].y;                                  \
                az += v[jj].z; aw += v[jj].w;                                  \
            }                                                                  \
        }                                                                      \
    }

    HALF(e0, d0, 0, 0)
    if (m > 8)  HALF(e0, d0, 8, 8)
    if (m > 16) HALF(e1, d1, 16, 0)
    if (m > 24) HALF(e1, d1, 24, 8)
    if (m > 32) HALF(e2, d2, 32, 0)
    if (m > 40) HALF(e2, d2, 40, 8)
#undef HALF

    // epilogue: row pre-scale, @W, bias, act, post-scale, nt-store
    ax *= pre; ay *= pre; az *= pre; aw *= pre;
    float ox = bv.x, oy = bv.y, oz = bv.z, ow = bv.w;
#pragma unroll
    for (int fg = 0; fg < 16; ++fg) {
        int sl = lb + fg;
        float a0 = __shfl(ax, sl);
        float a1 = __shfl(ay, sl);
        float a2 = __shfl(az, sl);
        float a3 = __shfl(aw, sl);
        float4 w0 = Wl[(fg * 4 + 0) * 16 + c];
        float4 w1 = Wl[(fg * 4 + 1) * 16 + c];
        float4 w2 = Wl[(fg * 4 + 2) * 16 + c];
        float4 w3 = Wl[(fg * 4 + 3) * 16 + c];
        ox = fmaf(a0, w0.x, ox); oy = fmaf(a0, w0.y, oy); oz = fmaf(a0, w0.z, oz); ow = fmaf(a0, w0.w, ow);
        ox = fmaf(a1, w1.x, ox); oy = fmaf(a1, w1.y, oy); oz = fmaf(a1, w1.z, oz); ow = fmaf(a1, w1.w, ow);
        ox = fmaf(a2, w2.x, ox); oy = fmaf(a2, w2.y, oy); oz = fmaf(a2, w2.z, oz); ow = fmaf(a2, w2.w, ow);
        ox = fmaf(a3, w3.x, ox); oy = fmaf(a3, w3.y, oy); oz = fmaf(a3, w3.z, oz); ow = fmaf(a3, w3.w, ow);
    }
    if (RELU) {
        ox = fmaxf(ox, 0.0f); oy = fmaxf(oy, 0.0f);
        oz = fmaxf(oz, 0.0f); ow = fmaxf(ow, 0.0f);
    }
    if (POST) {
        float p = postR[wid];
        ox *= p; oy *= p; oz *= p; ow *= p;
    }
    v4f o = {ox, oy, oz, ow};
    __builtin_nontemporal_store(o, (v4f*)(out + (size_t)wid * 64 + co));
}

// ---------------- per-channel sum / sumsq -----------------------------------
__global__ void k_stats(const float* __restrict__ h, float* __restrict__ stats) {
    int t = threadIdx.x;
    int f = t & 63;
    float s = 0.0f, sq = 0.0f;
    for (int i = blockIdx.x * blockDim.x + t; i < BNF_; i += gridDim.x * blockDim.x) {
        float v = h[i];
        s += v;
        sq += v * v;
    }
    __shared__ float ls[256], lq[256];
    ls[t] = s;
    lq[t] = sq;
    __syncthreads();
    if (t < 64) {
        s  = ls[t] + ls[t + 64] + ls[t + 128] + ls[t + 192];
        sq = lq[t] + lq[t + 64] + lq[t + 128] + lq[t + 192];
        atomicAdd(&stats[f], s);
        atomicAdd(&stats[64 + f], sq);
    }
}

// ---------------- BN scale/shift per channel --------------------------------
__global__ void k_bnfin(const float* __restrict__ stats, const float* __restrict__ gamma,
                        const float* __restrict__ beta, float* __restrict__ sc,
                        float* __restrict__ sh) {
    int f = threadIdx.x;
    if (f < 64) {
        float inv = 1.0f / (float)BN_;
        float mean = stats[f] * inv;
        float var  = stats[64 + f] * inv - mean * mean;
        float s = gamma[f] * rsqrtf(var + EPS_);
        sc[f] = s;
        sh[f] = beta[f] - mean * s;
    }
}

// ---------------- fused BN-apply + final linear -----------------------------
__global__ void k_final(const float* __restrict__ h, const float* __restrict__ linW,
                        const float* __restrict__ linb, const float* __restrict__ sc,
                        const float* __restrict__ sh, float* __restrict__ out) {
    int t = threadIdx.x;
    int base = blockIdx.x * (NF_ / 256);  // 4096 per block
    int f = (base + t) & 63;
    float s = sc[f], shv = sh[f];
    float acc[C_ * B_];
#pragma unroll
    for (int j = 0; j < C_ * B_; ++j) acc[j] = 0.0f;

    for (int k = 0; k < 16; ++k) {
        int i = base + k * 256 + t;
        float hv[B_];
#pragma unroll
        for (int b = 0; b < B_; ++b) hv[b] = fmaf(h[b * NF_ + i], s, shv);
#pragma unroll
        for (int c = 0; c < C_; ++c) {
            float w = __builtin_nontemporal_load(&linW[(size_t)c * NF_ + i]);
#pragma unroll
            for (int b = 0; b < B_; ++b) acc[c * B_ + b] = fmaf(hv[b], w, acc[c * B_ + b]);
        }
    }

    __shared__ float red[4][C_ * B_];
    int lane = t & 63, wv = t >> 6;
#pragma unroll
    for (int j = 0; j < C_ * B_; ++j) {
        float v = acc[j];
        v += __shfl_down(v, 32);
        v += __shfl_down(v, 16);
        v += __shfl_down(v, 8);
        v += __shfl_down(v, 4);
        v += __shfl_down(v, 2);
        v += __shfl_down(v, 1);
        if (lane == 0) red[wv][j] = v;
    }
    __syncthreads();
    if (t < C_ * B_) {
        float v = red[0][t] + red[1][t] + red[2][t] + red[3][t];
        int c = t / B_, b = t % B_;
        if (blockIdx.x == 0) v += linb[c];
        atomicAdd(&out[b * C_ + c], v);
    }
}

extern "C" void kernel_launch(void* const* d_in, const int* in_sizes, int n_in,
                              void* d_out, int out_size, void* d_ws, size_t ws_size,
                              hipStream_t stream) {
    const float* x        = (const float*)d_in[0];
    const int*   edge_src = (const int*)d_in[1];
    const int*   edge_dst = (const int*)d_in[2];
    const float* W1       = (const float*)d_in[3];
    const float* b1       = (const float*)d_in[4];
    const float* W2       = (const float*)d_in[5];
    const float* b2       = (const float*)d_in[6];
    const float* gamma    = (const float*)d_in[7];
    const float* beta     = (const float*)d_in[8];
    const float* linW     = (const float*)d_in[9];
    const float* linb     = (const float*)d_in[10];
    float* out = (float*)d_out;

    char* w = (char*)d_ws;
    float* degOr = (float*)w;           w += BN_ * 4;
    float* degIr = (float*)w;           w += BN_ * 4;
    int*   cntI  = (int*)w;             w += BN_ * 4;
    unsigned short* csr = (unsigned short*)w; w += (size_t)BN_ * CAP_ * 2;
    float* bufA  = (float*)w;           w += (size_t)BNF_ * 4;
    float* bufB  = (float*)w;           w += (size_t)BNF_ * 4;
    float* stats = (float*)w;           w += 128 * 4;
    float* sc    = (float*)w;           w += 64 * 4;
    float* sh    = (float*)w;           w += 64 * 4;

    // Build scratch aliases bufA/bufB (dead before conv1 writes bufA):
    unsigned int* partO   = (unsigned int*)bufA;
    unsigned int* partI   = partO + (size_t)B_ * NCH_ * NW_;
    unsigned int* baseArr = (unsigned int*)bufB;

    hipMemsetAsync(stats, 0, 128 * sizeof(float), stream);
    hipMemsetAsync(out, 0, B_ * C_ * sizeof(float), stream);

    // CSR build + degrees: two-phase privatized, zero global atomics
    k_count<<<B_ * NCH_, 256, 0, stream>>>(edge_src, edge_dst, partO, partI);
    k_offsets<<<BN_ / 4 / 256, 256, 0, stream>>>(partO, partI, baseArr, degOr, degIr, cntI);
    k_fill<<<B_ * NCH_, 256, 0, stream>>>(edge_src, edge_dst, baseArr, csr);

    // conv1: h1 = relu((sum degOr[s]*x[s]) * degIr @ W1 + b1) * degOr -> bufA
    k_conv<true, true, true><<<BN_ / 16, 256, 0, stream>>>(
        cntI, csr, x, degOr, degIr, degOr, W1, b1, bufA);

    // conv2: h2 = ((sum h1[s]) * degIr) @ W2 + b2 -> bufB
    k_conv<false, false, false><<<BN_ / 16, 256, 0, stream>>>(
        cntI, csr, bufA, degOr, degIr, degIr, W2, b2, bufB);

    // batchnorm stats + fused BN + final linear
    k_stats<<<256, 256, 0, stream>>>(bufB, stats);
    k_bnfin<<<1, 64, 0, stream>>>(stats, gamma, beta, sc, sh);
    k_final<<<256, 256, 0, stream>>>(bufB, linW, linb, sc, sh, out);
}

// Round 8
// 363.464 us; speedup vs baseline: 1.0515x; 1.0515x over previous
//
#include <hip/hip_runtime.h>

#define B_     8
#define N_     16384
#define F_     64
#define E_     262144
#define C_     10
#define NF_    (N_ * F_)        // 1048576
#define BN_    (B_ * N_)        // 131072
#define BNF_   (B_ * N_ * F_)   // 8388608
#define BE_    (B_ * E_)        // 2097152
#define CAP_   48               // padded CSR row capacity; P(Poisson(16) >= 48) ~ 6e-11
#define CHUNK_ 4096             // edges per build workgroup
#define NCH_   (E_ / CHUNK_)    // 64 chunks per batch
#define NW_    (N_ / 4)         // 4096 packed-u8 words per batch
#define EPS_   1e-5f

// ---------------- Build phase A: per-chunk privatized counts ----------------
__global__ __launch_bounds__(256) void k_count(const int* __restrict__ src,
                                               const int* __restrict__ dst,
                                               unsigned int* __restrict__ partO,
                                               unsigned int* __restrict__ partI) {
    __shared__ unsigned int pO[NW_];  // 16 KB
    __shared__ unsigned int pI[NW_];  // 16 KB
    int t = threadIdx.x;
    int b = blockIdx.x & 7, c = blockIdx.x >> 3;
    for (int i = t; i < NW_; i += 256) { pO[i] = 0; pI[i] = 0; }
    __syncthreads();
    const int* sb = src + (size_t)b * E_ + (size_t)c * CHUNK_;
    const int* db = dst + (size_t)b * E_ + (size_t)c * CHUNK_;
    for (int i = t; i < CHUNK_; i += 256) {
        int s = sb[i], d = db[i];
        atomicAdd(&pO[s >> 2], 1u << ((s & 3) * 8));
        atomicAdd(&pI[d >> 2], 1u << ((d & 3) * 8));
    }
    __syncthreads();
    size_t base = (size_t)(b * NCH_ + c) * NW_;
    for (int i = t; i < NW_; i += 256) {
        partO[base + i] = pO[i];
        partI[base + i] = pI[i];
    }
}

// ---------------- Build phase B: packed prefix over chunks + degrees --------
__global__ __launch_bounds__(256) void k_offsets(const unsigned int* __restrict__ partO,
                                                 const unsigned int* __restrict__ partI,
                                                 unsigned int* __restrict__ baseArr,
                                                 float* __restrict__ degOr,
                                                 float* __restrict__ degIr,
                                                 int* __restrict__ cntI_g) {
    int gw = blockIdx.x * 256 + threadIdx.x;  // word id in [0, BN_/4)
    int b = gw >> 12;
    int rw = gw & 4095;
    unsigned int sumI = 0, sumO = 0;
    for (int c = 0; c < NCH_; ++c) {
        size_t idx = (size_t)(b * NCH_ + c) * NW_ + rw;
        unsigned int wI = partI[idx];
        baseArr[idx] = sumI;  // exclusive prefix, packed u8 lanes
        sumI += wI;
        sumO += partO[idx];
    }
    int row0 = gw * 4;
#pragma unroll
    for (int r = 0; r < 4; ++r) {
        unsigned int ci = (sumI >> (r * 8)) & 0xFFu;
        unsigned int co = (sumO >> (r * 8)) & 0xFFu;
        degIr[row0 + r] = rsqrtf(fmaxf((float)ci, 1.0f));
        degOr[row0 + r] = rsqrtf(fmaxf((float)co, 1.0f));
        cntI_g[row0 + r] = (int)ci;
    }
}

// ---------------- Build phase C: deterministic-offset CSR fill --------------
__global__ __launch_bounds__(256) void k_fill(const int* __restrict__ src,
                                              const int* __restrict__ dst,
                                              const unsigned int* __restrict__ baseArr,
                                              unsigned short* __restrict__ csr) {
    __shared__ unsigned int cur[NW_];  // 16 KB
    __shared__ unsigned int bw[NW_];   // 16 KB
    int t = threadIdx.x;
    int b = blockIdx.x & 7, c = blockIdx.x >> 3;
    size_t pbase = (size_t)(b * NCH_ + c) * NW_;
    for (int i = t; i < NW_; i += 256) { cur[i] = 0; bw[i] = baseArr[pbase + i]; }
    __syncthreads();
    const int* sb = src + (size_t)b * E_ + (size_t)c * CHUNK_;
    const int* db = dst + (size_t)b * E_ + (size_t)c * CHUNK_;
    unsigned short* cb = csr + (size_t)b * N_ * CAP_;
    for (int i = t; i < CHUNK_; i += 256) {
        int s = sb[i], d = db[i];
        unsigned int sh = (d & 3) * 8;
        unsigned int old = atomicAdd(&cur[d >> 2], 1u << sh);
        unsigned int pos = ((old >> sh) & 0xFFu) + ((bw[d >> 2] >> sh) & 0xFFu);
        if (pos < CAP_) cb[d * CAP_ + pos] = (unsigned short)s;
    }
}

// ---------------- Dense mm: out = (in @ W) [* rowScale] ---------------------
// 256 threads, 16 rows/block. XCD swizzle: batch = blockIdx&7 so each batch's
// 4 MB slice stays in its XCD's L2 across the mm->gather->mm->gather chain.
// Thread owns column f for its wave's 4 rows; rows + W staged in LDS.
template <bool SCALE>
__global__ __launch_bounds__(256) void k_mmd(const float* __restrict__ in,
                                             const float* __restrict__ W,
                                             const float* __restrict__ rs,
                                             float* __restrict__ out) {
    __shared__ float Wl[4096];        // 16 KB
    __shared__ float4 rows[16][16];   // 4 KB  [row][kGroup]
    int t = threadIdx.x;
    int b = blockIdx.x & 7;
    int rowg = b * N_ + (blockIdx.x >> 3) * 16;  // global row base
    for (int i = t; i < 1024; i += 256) ((float4*)Wl)[i] = ((const float4*)W)[i];
    rows[t >> 4][t & 15] = ((const float4*)(in + (size_t)(rowg + (t >> 4)) * 64))[t & 15];
    __syncthreads();
    int f = t & 63;
    int wv = t >> 6;  // wave -> rows wv*4 .. wv*4+3
    float a0 = 0.0f, a1 = 0.0f, a2 = 0.0f, a3 = 0.0f;
#pragma unroll
    for (int kg = 0; kg < 16; ++kg) {
        float4 r0 = rows[wv * 4 + 0][kg];
        float4 r1 = rows[wv * 4 + 1][kg];
        float4 r2 = rows[wv * 4 + 2][kg];
        float4 r3 = rows[wv * 4 + 3][kg];
        float w0 = Wl[(kg * 4 + 0) * 64 + f];
        float w1 = Wl[(kg * 4 + 1) * 64 + f];
        float w2 = Wl[(kg * 4 + 2) * 64 + f];
        float w3 = Wl[(kg * 4 + 3) * 64 + f];
        a0 = fmaf(r0.x, w0, a0); a0 = fmaf(r0.y, w1, a0); a0 = fmaf(r0.z, w2, a0); a0 = fmaf(r0.w, w3, a0);
        a1 = fmaf(r1.x, w0, a1); a1 = fmaf(r1.y, w1, a1); a1 = fmaf(r1.z, w2, a1); a1 = fmaf(r1.w, w3, a1);
        a2 = fmaf(r2.x, w0, a2); a2 = fmaf(r2.y, w1, a2); a2 = fmaf(r2.z, w2, a2); a2 = fmaf(r2.w, w3, a2);
        a3 = fmaf(r3.x, w0, a3); a3 = fmaf(r3.y, w1, a3); a3 = fmaf(r3.z, w2, a3); a3 = fmaf(r3.w, w3, a3);
    }
    int r0i = rowg + wv * 4;
    if (SCALE) {
        a0 *= rs[r0i]; a1 *= rs[r0i + 1]; a2 *= rs[r0i + 2]; a3 *= rs[r0i + 3];
    }
    out[(size_t)(r0i + 0) * 64 + f] = a0;
    out[(size_t)(r0i + 1) * 64 + f] = a1;
    out[(size_t)(r0i + 2) * 64 + f] = a2;
    out[(size_t)(r0i + 3) * 64 + f] = a3;
}

// ---------------- Lean gather: g[r] = sum_{e in row r} z[src_e] + epilogue --
// 256 threads = 4 waves; wave handles 4 rows. Lane: r = lane>>4, c = lane&15
// (float4 group). Per 8 edges: 8 bpermute + 8 predicated dwordx4 + 32 adds.
// No W, no LDS. Epilogue per-lane only:
//   CONV1: out = relu(g*degIr + b1) * degOr     CONV2: out = g*degIr + b2
template <bool CONV1>
__global__ __launch_bounds__(256, 8) void k_gat(
        const int* __restrict__ cnt, const unsigned short* __restrict__ csr,
        const float* __restrict__ z, const float* __restrict__ degIr,
        const float* __restrict__ degOr, const float* __restrict__ bias,
        float* __restrict__ out) {
    int t = threadIdx.x;
    int lane = t & 63;
    int wave = t >> 6;
    int c = lane & 15;
    int b = blockIdx.x & 7;  // XCD swizzle: batch slice L2-resident
    int row = (blockIdx.x >> 3) * 16 + wave * 4 + (lane >> 4);
    int wid = b * N_ + row;
    const float* zb = z + (size_t)b * NF_;
    int lb = lane & 48;
    int co = c * 4;

    int n = cnt[wid];
    if (n > CAP_) n = CAP_;
    size_t cb = (size_t)wid * CAP_;
    int e0 = csr[cb + c] & 0x3FFF;        // mask: entries >= n may be stale
    int e1 = csr[cb + 16 + c] & 0x3FFF;
    int e2 = csr[cb + 32 + c] & 0x3FFF;
    float dIr = degIr[wid];               // early loads overlap gather
    const float4 bv = ((const float4*)bias)[c];
    int m = n;  // wave-uniform max count across the 4 rows
    m = max(m, __shfl_xor(m, 16));
    m = max(m, __shfl_xor(m, 32));

    float ax = 0.0f, ay = 0.0f, az = 0.0f, aw = 0.0f;

#define HALF(EREG, KOFF, JBASE)                                                \
    {                                                                          \
        float4 v[8];                                                           \
        int rem = n - (KOFF);                                                  \
        _Pragma("unroll")                                                      \
        for (int jj = 0; jj < 8; ++jj) {                                       \
            int s = __shfl(EREG, lb + (JBASE) + jj);                           \
            v[jj] = make_float4(0.0f, 0.0f, 0.0f, 0.0f);                       \
            if (jj < rem) v[jj] = *(const float4*)(zb + s * 64 + co);          \
        }                                                                      \
        _Pragma("unroll")                                                      \
        for (int jj = 0; jj < 8; ++jj) {                                       \
            ax += v[jj].x; ay += v[jj].y; az += v[jj].z; aw += v[jj].w;        \
        }                                                                      \
    }

    HALF(e0, 0, 0)
    if (m > 8)  HALF(e0, 8, 8)
    if (m > 16) HALF(e1, 16, 0)
    if (m > 24) HALF(e1, 24, 8)
    if (m > 32) HALF(e2, 32, 0)
    if (m > 40) HALF(e2, 40, 8)
#undef HALF

    float ox, oy, oz, ow;
    if (CONV1) {
        float po = degOr[wid];
        ox = fmaxf(fmaf(ax, dIr, bv.x), 0.0f) * po;
        oy = fmaxf(fmaf(ay, dIr, bv.y), 0.0f) * po;
        oz = fmaxf(fmaf(az, dIr, bv.z), 0.0f) * po;
        ow = fmaxf(fmaf(aw, dIr, bv.w), 0.0f) * po;
    } else {
        ox = fmaf(ax, dIr, bv.x);
        oy = fmaf(ay, dIr, bv.y);
        oz = fmaf(az, dIr, bv.z);
        ow = fmaf(aw, dIr, bv.w);
    }
    float4 o; o.x = ox; o.y = oy; o.z = oz; o.w = ow;
    *(float4*)(out + (size_t)wid * 64 + co) = o;
}

// ---------------- per-channel sum / sumsq -----------------------------------
__global__ void k_stats(const float* __restrict__ h, float* __restrict__ stats) {
    int t = threadIdx.x;
    int f = t & 63;
    float s = 0.0f, sq = 0.0f;
    for (int i = blockIdx.x * blockDim.x + t; i < BNF_; i += gridDim.x * blockDim.x) {
        float v = h[i];
        s += v;
        sq += v * v;
    }
    __shared__ float ls[256], lq[256];
    ls[t] = s;
    lq[t] = sq;
    __syncthreads();
    if (t < 64) {
        s  = ls[t] + ls[t + 64] + ls[t + 128] + ls[t + 192];
        sq = lq[t] + lq[t + 64] + lq[t + 128] + lq[t + 192];
        atomicAdd(&stats[f], s);
        atomicAdd(&stats[64 + f], sq);
    }
}

// ---------------- BN scale/shift per channel --------------------------------
__global__ void k_bnfin(const float* __restrict__ stats, const float* __restrict__ gamma,
                        const float* __restrict__ beta, float* __restrict__ sc,
                        float* __restrict__ sh) {
    int f = threadIdx.x;
    if (f < 64) {
        float inv = 1.0f / (float)BN_;
        float mean = stats[f] * inv;
        float var  = stats[64 + f] * inv - mean * mean;
        float s = gamma[f] * rsqrtf(var + EPS_);
        sc[f] = s;
        sh[f] = beta[f] - mean * s;
    }
}

// ---------------- fused BN-apply + final linear -----------------------------
__global__ void k_final(const float* __restrict__ h, const float* __restrict__ linW,
                        const float* __restrict__ linb, const float* __restrict__ sc,
                        const float* __restrict__ sh, float* __restrict__ out) {
    int t = threadIdx.x;
    int base = blockIdx.x * (NF_ / 256);  // 4096 per block
    int f = (base + t) & 63;
    float s = sc[f], shv = sh[f];
    float acc[C_ * B_];
#pragma unroll
    for (int j = 0; j < C_ * B_; ++j) acc[j] = 0.0f;

    for (int k = 0; k < 16; ++k) {
        int i = base + k * 256 + t;
        float hv[B_];
#pragma unroll
        for (int b = 0; b < B_; ++b) hv[b] = fmaf(h[b * NF_ + i], s, shv);
#pragma unroll
        for (int c = 0; c < C_; ++c) {
            float w = linW[(size_t)c * NF_ + i];
#pragma unroll
            for (int b = 0; b < B_; ++b) acc[c * B_ + b] = fmaf(hv[b], w, acc[c * B_ + b]);
        }
    }

    __shared__ float red[4][C_ * B_];
    int lane = t & 63, wv = t >> 6;
#pragma unroll
    for (int j = 0; j < C_ * B_; ++j) {
        float v = acc[j];
        v += __shfl_down(v, 32);
        v += __shfl_down(v, 16);
        v += __shfl_down(v, 8);
        v += __shfl_down(v, 4);
        v += __shfl_down(v, 2);
        v += __shfl_down(v, 1);
        if (lane == 0) red[wv][j] = v;
    }
    __syncthreads();
    if (t < C_ * B_) {
        float v = red[0][t] + red[1][t] + red[2][t] + red[3][t];
        int c = t / B_, b = t % B_;
        if (blockIdx.x == 0) v += linb[c];
        atomicAdd(&out[b * C_ + c], v);
    }
}

extern "C" void kernel_launch(void* const* d_in, const int* in_sizes, int n_in,
                              void* d_out, int out_size, void* d_ws, size_t ws_size,
                              hipStream_t stream) {
    const float* x        = (const float*)d_in[0];
    const int*   edge_src = (const int*)d_in[1];
    const int*   edge_dst = (const int*)d_in[2];
    const float* W1       = (const float*)d_in[3];
    const float* b1       = (const float*)d_in[4];
    const float* W2       = (const float*)d_in[5];
    const float* b2       = (const float*)d_in[6];
    const float* gamma    = (const float*)d_in[7];
    const float* beta     = (const float*)d_in[8];
    const float* linW     = (const float*)d_in[9];
    const float* linb     = (const float*)d_in[10];
    float* out = (float*)d_out;

    char* w = (char*)d_ws;
    float* degOr = (float*)w;           w += BN_ * 4;
    float* degIr = (float*)w;           w += BN_ * 4;
    int*   cntI  = (int*)w;             w += BN_ * 4;
    unsigned short* csr = (unsigned short*)w; w += (size_t)BN_ * CAP_ * 2;
    float* bufA  = (float*)w;           w += (size_t)BNF_ * 4;
    float* bufB  = (float*)w;           w += (size_t)BNF_ * 4;
    float* stats = (float*)w;           w += 128 * 4;
    float* sc    = (float*)w;           w += 64 * 4;
    float* sh    = (float*)w;           w += 64 * 4;

    // Build scratch aliases bufA/bufB (dead before mm1 writes bufA):
    unsigned int* partO   = (unsigned int*)bufA;
    unsigned int* partI   = partO + (size_t)B_ * NCH_ * NW_;
    unsigned int* baseArr = (unsigned int*)bufB;

    hipMemsetAsync(stats, 0, 128 * sizeof(float), stream);
    hipMemsetAsync(out, 0, B_ * C_ * sizeof(float), stream);

    // CSR build + degrees: two-phase privatized, zero global atomics
    k_count<<<B_ * NCH_, 256, 0, stream>>>(edge_src, edge_dst, partO, partI);
    k_offsets<<<BN_ / 4 / 256, 256, 0, stream>>>(partO, partI, baseArr, degOr, degIr, cntI);
    k_fill<<<B_ * NCH_, 256, 0, stream>>>(edge_src, edge_dst, baseArr, csr);

    // conv1 = relu(degIr * A (degOr * x @ W1) + b1); pre-scale degOr for conv2
    k_mmd<true><<<BN_ / 16, 256, 0, stream>>>(x, W1, degOr, bufA);          // z1
    k_gat<true><<<BN_ / 16, 256, 0, stream>>>(cntI, csr, bufA, degIr, degOr, b1, bufB);  // h1z

    // conv2 = degIr * A (h1z @ W2) + b2
    k_mmd<false><<<BN_ / 16, 256, 0, stream>>>(bufB, W2, nullptr, bufA);    // z2
    k_gat<false><<<BN_ / 16, 256, 0, stream>>>(cntI, csr, bufA, degIr, degOr, b2, bufB); // h2

    // batchnorm stats + fused BN + final linear
    k_stats<<<256, 256, 0, stream>>>(bufB, stats);
    k_bnfin<<<1, 64, 0, stream>>>(stats, gamma, beta, sc, sh);
    k_final<<<256, 256, 0, stream>>>(bufB, linW, linb, sc, sh, out);
}